// Round 10
// baseline (303.884 us; speedup 1.0000x reference)
//
#include <hip/hip_runtime.h>

#define N_NODES 50000
#define N_EDGES 800000
#define DIM 128
#define NCLS 40

// chunked CSR build
#define NCHUNK 64          // halved vs R9: cnt buffer 12.85 -> 6.4 MB
#define CE 12500           // NCHUNK*CE == N_EDGES exactly
#define HALF_N 25088       // nodes per half (2*WHALF)
#define WHALF 12544        // packed u32 words per half (= 49*256)
#define SCAN_B 98          // scan blocks (2 halves * 49)
#define NSEG 4             // chunk-axis segments
#define SEGC 16            // NCHUNK / NSEG
#define N_PAD 50432        // >= 2*HALF_N padded node arrays

typedef __bf16 bf16x8_t __attribute__((ext_vector_type(8)));
typedef unsigned short us8_t __attribute__((ext_vector_type(8)));
typedef float f32x4_t __attribute__((ext_vector_type(4)));

static __device__ __forceinline__ float b2f(unsigned short h) {
    unsigned u = ((unsigned)h) << 16;
    return __builtin_bit_cast(float, u);
}
static __device__ __forceinline__ unsigned short f2b(float f) {
    unsigned u = __builtin_bit_cast(unsigned, f);
    u += 0x7FFFu + ((u >> 16) & 1u);   // RNE; values finite O(1)
    return (unsigned short)(u >> 16);
}

// ---------------- merged prep: bf16 shadow + weight repack + chunk_count ----------------
// blocks [0,3125): to_bf16 of h (3125*256*8 = 6.4M exact)          [no LDS use]
// blocks [3125,3301): repack w0/w1/w2/wp into MFMA fragment order  [no LDS use]
// blocks [3301,3429): per-chunk per-node edge counts (LDS atomics) [50 KB LDS]
// Merge rationale: count blocks co-schedule with BW-bound stream blocks
// (independent work), deleting one serial dispatch. 50KB static LDS caps
// occupancy at 3 blocks/CU -- still ~768 resident streaming blocks (BW-sat).
#define PREP_B 3125
#define REPACK_B 176
#define CNT_B 128          // NCHUNK * 2 halves
__global__ __launch_bounds__(256) void prep(const float* __restrict__ hsrc,
                                            unsigned short* __restrict__ hout,
                                            const float* __restrict__ w0,
                                            const float* __restrict__ w1,
                                            const float* __restrict__ w2,
                                            const float* __restrict__ wp,
                                            unsigned short* __restrict__ f0h,
                                            unsigned short* __restrict__ f0l,
                                            unsigned short* __restrict__ f1h,
                                            unsigned short* __restrict__ f1l,
                                            unsigned short* __restrict__ f2h,
                                            unsigned short* __restrict__ f2l,
                                            unsigned short* __restrict__ fph,
                                            unsigned short* __restrict__ fpl,
                                            const int* __restrict__ edst,
                                            unsigned* __restrict__ cnt,
                                            int* __restrict__ partial) {
    __shared__ unsigned lds[WHALF];   // 50 KB (used only by count blocks)
    if (blockIdx.x < PREP_B) {
        size_t e0 = ((size_t)blockIdx.x * 256 + threadIdx.x) * 8;
        f32x4_t v0 = *(const f32x4_t*)(hsrc + e0);
        f32x4_t v1 = *(const f32x4_t*)(hsrc + e0 + 4);
        us8_t o;
        #pragma unroll
        for (int j = 0; j < 4; ++j) { o[j] = f2b(v0[j]); o[4 + j] = f2b(v1[j]); }
        *(us8_t*)(hout + e0) = o;
        return;
    }
    if (blockIdx.x >= PREP_B + REPACK_B) {
        // ---- chunk_count ----
        int cc = blockIdx.x - PREP_B - REPACK_B;   // [0,128)
        int c = cc & (NCHUNK - 1), h = cc >> 6, tid = threadIdx.x;
        if (cc == 0 && tid < 128) partial[tid] = 0;
        for (int w = tid; w < WHALF; w += 256) lds[w] = 0;
        __syncthreads();
        int base = c * CE;
        for (int k = tid; k < CE; k += 256) {
            int local = edst[base + k] - h * HALF_N;
            if (local >= 0 && local < HALF_N)
                atomicAdd(&lds[local >> 1], 1u << ((local & 1) * 16));
        }
        __syncthreads();
        unsigned* out = cnt + ((size_t)(h * NCHUNK + c)) * WHALF;
        for (int w = tid; w < WHALF; w += 256) out[w] = lds[w];
        return;
    }
    // ---- weight repack ----
    int t = (blockIdx.x - PREP_B) * 256 + threadIdx.x;
    const float* src;
    unsigned short *dh, *dl;
    int idx, ncols;
    if (t < 16384)      { src = w0; dh = f0h; dl = f0l; idx = t;         ncols = 128; }
    else if (t < 32768) { src = w1; dh = f1h; dl = f1l; idx = t - 16384; ncols = 128; }
    else if (t < 38912) { src = w2; dh = f2h; dl = f2l; idx = t - 32768; ncols = 48; }
    else if (t < 45056) { src = wp; dh = fph; dl = fpl; idx = t - 38912; ncols = 48; }
    else return;
    int k = idx / ncols, n = idx - k * ncols;
    float v;
    if (ncols == 128) v = src[k * 128 + n];
    else              v = (n < NCLS) ? src[k * NCLS + n] : 0.f;
    int nt = n >> 4, m = n & 15, kt = k >> 5, quad = (k >> 3) & 3, j = k & 7;
    int off = ((nt * 4 + kt) * 64 + quad * 16 + m) * 8 + j;
    unsigned short hi = f2b(v);
    dh[off] = hi;
    dl[off] = f2b(v - b2f(hi));
}

// ---------------- segmented scan over chunk axis: 392 blocks, 16-iter chains ----------------
__global__ __launch_bounds__(256) void cscan_seg(unsigned* __restrict__ cnt,
                                                 unsigned* __restrict__ segsum,
                                                 int* __restrict__ partial) {
    int bx = blockIdx.x;
    int seg = bx / SCAN_B;
    int b = bx - seg * SCAN_B;
    int h = b / 49;
    int w = (b % 49) * 256 + threadIdx.x;
    unsigned acc = 0;
    int c0 = seg * SEGC;
    for (int c = c0; c < c0 + SEGC; ++c) {
        size_t idx = ((size_t)(h * NCHUNK + c)) * WHALF + w;
        unsigned v = cnt[idx];
        cnt[idx] = acc;          // segment-local exclusive prefix (packed halves)
        acc += v;
    }
    segsum[((size_t)(seg * 2 + h)) * WHALF + w] = acc;
    __shared__ int lds[256];
    lds[threadIdx.x] = (int)(acc & 0xFFFFu) + (int)(acc >> 16);
    __syncthreads();
    #pragma unroll
    for (int off = 128; off > 0; off >>= 1) {
        if (threadIdx.x < off) lds[threadIdx.x] += lds[threadIdx.x + off];
        __syncthreads();
    }
    if (threadIdx.x == 0) atomicAdd(&partial[b], lds[0]);
}

// ---------------- final node-axis scan: seg prefix -> segoff; rs / deg / dinv ----------------
__global__ __launch_bounds__(256) void scan_final(const unsigned* __restrict__ segsum,
                                                  unsigned* __restrict__ segoff,
                                                  const int* __restrict__ partial,
                                                  int* __restrict__ rs,
                                                  int* __restrict__ deg,
                                                  float* __restrict__ dinv) {
    __shared__ int lds[256];
    int b = blockIdx.x;
    int h = b / 49;
    int tid = threadIdx.x;
    int w = (b % 49) * 256 + tid;
    lds[tid] = (tid < b && tid < 128) ? partial[tid] : 0;
    __syncthreads();
    #pragma unroll
    for (int off = 128; off > 0; off >>= 1) {
        if (tid < off) lds[tid] += lds[tid + off];
        __syncthreads();
    }
    int boff = lds[0];
    __syncthreads();
    // segment prefix (packed u16 halves; per-node total < 2^16 so no cross-carry)
    unsigned run = 0;
    #pragma unroll
    for (int s = 0; s < NSEG; ++s) {
        unsigned sv = segsum[((size_t)(s * 2 + h)) * WHALF + w];
        segoff[((size_t)(s * 2 + h)) * WHALF + w] = run;
        run += sv;
    }
    unsigned dp = run;
    int lo = (int)(dp & 0xFFFFu), hi = (int)(dp >> 16);
    int s = lo + hi;
    lds[tid] = s;
    __syncthreads();
    #pragma unroll
    for (int off = 1; off < 256; off <<= 1) {
        int v = lds[tid];
        int add = (tid >= off) ? lds[tid - off] : 0;
        __syncthreads();
        lds[tid] = v + add;
        __syncthreads();
    }
    int excl = boff + lds[tid] - s;
    int n0 = h * HALF_N + 2 * w;
    rs[n0] = excl;
    rs[n0 + 1] = excl + lo;
    deg[n0] = lo;
    deg[n0 + 1] = hi;
    dinv[n0] = (lo > 0) ? (1.0f / (float)lo) : 0.0f;
    dinv[n0 + 1] = (hi > 0) ? (1.0f / (float)hi) : 0.0f;
}

// ---------------- CSR fill: rank via LDS returning atomics; blockIdx.y = half ----------------
__global__ __launch_bounds__(256) void fill2(const int* __restrict__ src,
                                             const int* __restrict__ dst,
                                             const float* __restrict__ mask,
                                             const unsigned* __restrict__ cnt,
                                             const unsigned* __restrict__ segoff,
                                             const int* __restrict__ rs,
                                             unsigned* __restrict__ csr) {
    __shared__ unsigned cur[WHALF];   // 50 KB
    int c = blockIdx.x, h = blockIdx.y, tid = threadIdx.x;
    int seg = c >> 4;                 // c / SEGC (SEGC=16)
    const unsigned* off = cnt + ((size_t)(h * NCHUNK + c)) * WHALF;
    const unsigned* soff = segoff + ((size_t)(seg * 2 + h)) * WHALF;
    for (int w = tid; w < WHALF; w += 256) cur[w] = off[w] + soff[w];  // packed add, no carry
    __syncthreads();
    int base = c * CE;
    for (int k = tid; k < CE; k += 256) {
        int e = base + k;
        int d = dst[e];
        int local = d - h * HALF_N;
        if (local >= 0 && local < HALF_N) {
            unsigned sm = (unsigned)src[e] | ((unsigned)f2b(mask[e]) << 16);
            int sh = (local & 1) * 16;
            unsigned old = atomicAdd(&cur[local >> 1], 1u << sh);
            int rank = (int)((old >> sh) & 0xFFFFu);
            csr[rs[d] + rank] = sm;
        }
    }
}

// ---------------- gather primitives ----------------
static __device__ __forceinline__ void issue16(const unsigned short* __restrict__ xb,
                                               unsigned pk, int lane, unsigned* vv) {
    #pragma unroll
    for (int j = 0; j < 16; ++j) {
        unsigned p = (unsigned)__builtin_amdgcn_readlane((int)pk, j);  // 0 for j>=nb
        vv[j] = *(const unsigned*)(xb + (size_t)(p & 0xFFFFu) * DIM + lane * 2);
    }
}
static __device__ __forceinline__ void accum16(unsigned pk, const unsigned* vv,
                                               float& acc0, float& acc1) {
    #pragma unroll
    for (int j = 0; j < 16; ++j) {
        unsigned p = (unsigned)__builtin_amdgcn_readlane((int)pk, j);
        float mm = b2f((unsigned short)(p >> 16));                     // 0 for j>=nb
        acc0 += mm * b2f((unsigned short)(vv[j] & 0xFFFFu));
        acc1 += mm * b2f((unsigned short)(vv[j] >> 16));
    }
}

// ---------------- software-pipelined gather of 4 consecutive nodes into LDS ----------------
template<bool RES32>
static __device__ __forceinline__ void gather4(const unsigned short* __restrict__ xb,
                                               const float* __restrict__ xres,
                                               const unsigned short* __restrict__ xlo,
                                               const int* __restrict__ rs,
                                               const int* __restrict__ deg,
                                               const float* __restrict__ dinv,
                                               const unsigned* __restrict__ csr,
                                               int nb0, int lane,
                                               float (*ldsrow)[132], int row0) {
    int rs4[4], dg4[4];
    float di4[4];
    #pragma unroll
    for (int i = 0; i < 4; ++i) {
        int n = nb0 + i;
        rs4[i] = rs[n];
        dg4[i] = deg[n];
        di4[i] = dinv[n];
    }
    unsigned pk0, pk1, pk2, pk3;
    pk0 = (lane < (dg4[0] < 16 ? dg4[0] : 16)) ? csr[rs4[0] + lane] : 0u;
    pk1 = (lane < (dg4[1] < 16 ? dg4[1] : 16)) ? csr[rs4[1] + lane] : 0u;

    unsigned vvA[16], vvB[16];
    issue16(xb, pk0, lane, vvA);       // node 0 features in flight

    unsigned pkq[4] = {pk0, pk1, 0u, 0u};
    #pragma unroll
    for (int i = 0; i < 4; ++i) {
        if (i == 0) pk2 = (lane < (dg4[2] < 16 ? dg4[2] : 16)) ? csr[rs4[2] + lane] : 0u;
        if (i == 1) pk3 = (lane < (dg4[3] < 16 ? dg4[3] : 16)) ? csr[rs4[3] + lane] : 0u;
        if (i == 0) pkq[2] = pk2;
        if (i == 1) pkq[3] = pk3;
        if (i < 3) issue16(xb, pkq[i + 1], lane, (i & 1) ? vvA : vvB);  // next node in flight
        float acc0 = 0.f, acc1 = 0.f;
        accum16(pkq[i], (i & 1) ? vvB : vvA, acc0, acc1);
        // extra chunks (deg > 16), serial (rarer path)
        for (int base = 16; base < dg4[i]; base += 16) {
            int nb = dg4[i] - base;
            if (nb > 16) nb = 16;
            unsigned pke = (lane < nb) ? csr[rs4[i] + base + lane] : 0u;
            unsigned vvE[16];
            issue16(xb, pke, lane, vvE);
            accum16(pke, vvE, acc0, acc1);
        }
        float di = di4[i];
        float x0, x1;
        if constexpr (RES32) {
            float2 xp = *(const float2*)(xres + (size_t)(nb0 + i) * DIM + lane * 2);
            x0 = xp.x; x1 = xp.y;
        } else {
            unsigned hv = *(const unsigned*)(xb  + (size_t)(nb0 + i) * DIM + lane * 2);
            unsigned lv = *(const unsigned*)(xlo + (size_t)(nb0 + i) * DIM + lane * 2);
            x0 = b2f((unsigned short)(hv & 0xFFFFu)) + b2f((unsigned short)(lv & 0xFFFFu));
            x1 = b2f((unsigned short)(hv >> 16))     + b2f((unsigned short)(lv >> 16));
        }
        ldsrow[row0 + i][lane * 2]     = x0 + acc0 * di;
        ldsrow[row0 + i][lane * 2 + 1] = x1 + acc1 * di;
    }
}

// ---------------- fused agg + GEMM[N,128]x[128,128] + BN + ReLU ----------------
template<bool RES32>
__global__ __launch_bounds__(256) void fused_layer(const unsigned short* __restrict__ xb,
                                                   const float* __restrict__ xres,
                                                   const unsigned short* __restrict__ xlo,
                                                   const int* __restrict__ rs,
                                                   const int* __restrict__ deg,
                                                   const float* __restrict__ dinv,
                                                   const unsigned* __restrict__ csr,
                                                   const unsigned short* __restrict__ wfh,
                                                   const unsigned short* __restrict__ wfl,
                                                   const float* __restrict__ bias,
                                                   const float* __restrict__ gam,
                                                   const float* __restrict__ bet,
                                                   const float* __restrict__ rm,
                                                   const float* __restrict__ rv,
                                                   unsigned short* __restrict__ outhi,
                                                   unsigned short* __restrict__ outlo) {
    __shared__ float lds[16][132];   // 8.4 KB
    int tid = threadIdx.x;
    int wave = tid >> 6, lane = tid & 63;
    int rbase = blockIdx.x * 16;     // 3125 * 16 == 50000 exactly

    gather4<RES32>(xb, xres, xlo, rs, deg, dinv, csr, rbase + wave * 4, lane, lds, wave * 4);
    __syncthreads();   // cross-lane LDS dependency: barrier REQUIRED

    int m = lane & 15, quad = lane >> 4;
    const float* ap = &lds[m][0];

    us8_t ah[4], al[4];
    #pragma unroll
    for (int kt = 0; kt < 4; ++kt) {
        f32x4_t p0 = *(const f32x4_t*)(ap + kt * 32 + quad * 8);
        f32x4_t p1 = *(const f32x4_t*)(ap + kt * 32 + quad * 8 + 4);
        #pragma unroll
        for (int j = 0; j < 4; ++j) {
            unsigned short h0 = f2b(p0[j]);
            unsigned short h1 = f2b(p1[j]);
            ah[kt][j] = h0;
            ah[kt][4 + j] = h1;
            al[kt][j] = f2b(p0[j] - b2f(h0));
            al[kt][4 + j] = f2b(p1[j] - b2f(h1));
        }
    }

    f32x4_t acc[2] = {};
    #pragma unroll
    for (int kt = 0; kt < 4; ++kt) {
        #pragma unroll
        for (int t = 0; t < 2; ++t) {
            int nt = wave * 2 + t;
            int boff = ((nt * 4 + kt) * 64 + lane) * 8;
            us8_t bh = *(const us8_t*)(wfh + boff);
            us8_t bl = *(const us8_t*)(wfl + boff);
            acc[t] = __builtin_amdgcn_mfma_f32_16x16x32_bf16(
                __builtin_bit_cast(bf16x8_t, ah[kt]),
                __builtin_bit_cast(bf16x8_t, bh), acc[t], 0, 0, 0);
            acc[t] = __builtin_amdgcn_mfma_f32_16x16x32_bf16(
                __builtin_bit_cast(bf16x8_t, ah[kt]),
                __builtin_bit_cast(bf16x8_t, bl), acc[t], 0, 0, 0);
            acc[t] = __builtin_amdgcn_mfma_f32_16x16x32_bf16(
                __builtin_bit_cast(bf16x8_t, al[kt]),
                __builtin_bit_cast(bf16x8_t, bh), acc[t], 0, 0, 0);
        }
    }

    #pragma unroll
    for (int t = 0; t < 2; ++t) {
        int nt = wave * 2 + t;
        int j = nt * 16 + m;
        float bj = bias[j];
        float sc = gam[j] * rsqrtf(rv[j] + 1e-5f);
        float sh = bet[j] - rm[j] * sc;
        #pragma unroll
        for (int i = 0; i < 4; ++i) {
            int r = rbase + quad * 4 + i;
            float z = fmaxf((acc[t][i] + bj) * sc + sh, 0.f);
            unsigned short zh = f2b(z);
            outhi[(size_t)r * DIM + j] = zh;
            outlo[(size_t)r * DIM + j] = f2b(z - b2f(zh));
        }
    }
}

// ---------------- fused final ----------------
__global__ __launch_bounds__(256) void fused_final2(const unsigned short* __restrict__ xb,
                                                    const unsigned short* __restrict__ xlo,
                                                    const int* __restrict__ rs,
                                                    const int* __restrict__ deg,
                                                    const float* __restrict__ dinv,
                                                    const unsigned* __restrict__ csr,
                                                    const unsigned short* __restrict__ f2h,
                                                    const unsigned short* __restrict__ f2l,
                                                    const unsigned short* __restrict__ fph,
                                                    const unsigned short* __restrict__ fpl,
                                                    const float* __restrict__ b2,
                                                    const float* __restrict__ g2,
                                                    const float* __restrict__ be2,
                                                    const float* __restrict__ rm2,
                                                    const float* __restrict__ rv2,
                                                    const float* __restrict__ bp,
                                                    float* __restrict__ out) {
    __shared__ float lds[16][132];
    int tid = threadIdx.x;
    int wave = tid >> 6, lane = tid & 63;
    int rbase = blockIdx.x * 16;

    gather4<false>(xb, nullptr, xlo, rs, deg, dinv, csr, rbase + wave * 4, lane, lds, wave * 4);
    __syncthreads();

    if (wave == 3) return;   // waves 0..2 handle the 3 col-tiles

    int m = lane & 15, quad = lane >> 4;
    int arow = rbase + m;
    const float* ap2 = &lds[m][0];
    const unsigned short* aphh = xb  + (size_t)arow * DIM;
    const unsigned short* aphl = xlo + (size_t)arow * DIM;

    us8_t a2h[4], a2l[4], ahh[4], ahl[4];
    #pragma unroll
    for (int kt = 0; kt < 4; ++kt) {
        f32x4_t p0 = *(const f32x4_t*)(ap2 + kt * 32 + quad * 8);
        f32x4_t p1 = *(const f32x4_t*)(ap2 + kt * 32 + quad * 8 + 4);
        ahh[kt] = *(const us8_t*)(aphh + kt * 32 + quad * 8);   // direct hi fragment
        ahl[kt] = *(const us8_t*)(aphl + kt * 32 + quad * 8);   // direct lo fragment
        #pragma unroll
        for (int j = 0; j < 4; ++j) {
            unsigned short h0 = f2b(p0[j]), h1 = f2b(p1[j]);
            a2h[kt][j] = h0; a2h[kt][4 + j] = h1;
            a2l[kt][j] = f2b(p0[j] - b2f(h0));
            a2l[kt][4 + j] = f2b(p1[j] - b2f(h1));
        }
    }

    int nt = wave;           // 0..2
    f32x4_t acc2 = {};
    f32x4_t accp = {};
    #pragma unroll
    for (int kt = 0; kt < 4; ++kt) {
        int boff = ((nt * 4 + kt) * 64 + lane) * 8;
        us8_t b2hv = *(const us8_t*)(f2h + boff);
        us8_t b2lv = *(const us8_t*)(f2l + boff);
        us8_t bphv = *(const us8_t*)(fph + boff);
        us8_t bplv = *(const us8_t*)(fpl + boff);
        acc2 = __builtin_amdgcn_mfma_f32_16x16x32_bf16(
            __builtin_bit_cast(bf16x8_t, a2h[kt]),
            __builtin_bit_cast(bf16x8_t, b2hv), acc2, 0, 0, 0);
        acc2 = __builtin_amdgcn_mfma_f32_16x16x32_bf16(
            __builtin_bit_cast(bf16x8_t, a2h[kt]),
            __builtin_bit_cast(bf16x8_t, b2lv), acc2, 0, 0, 0);
        acc2 = __builtin_amdgcn_mfma_f32_16x16x32_bf16(
            __builtin_bit_cast(bf16x8_t, a2l[kt]),
            __builtin_bit_cast(bf16x8_t, b2hv), acc2, 0, 0, 0);
        accp = __builtin_amdgcn_mfma_f32_16x16x32_bf16(
            __builtin_bit_cast(bf16x8_t, ahh[kt]),
            __builtin_bit_cast(bf16x8_t, bphv), accp, 0, 0, 0);
        accp = __builtin_amdgcn_mfma_f32_16x16x32_bf16(
            __builtin_bit_cast(bf16x8_t, ahh[kt]),
            __builtin_bit_cast(bf16x8_t, bplv), accp, 0, 0, 0);
        accp = __builtin_amdgcn_mfma_f32_16x16x32_bf16(
            __builtin_bit_cast(bf16x8_t, ahl[kt]),
            __builtin_bit_cast(bf16x8_t, bphv), accp, 0, 0, 0);
    }

    int j = nt * 16 + m;
    if (j < NCLS) {
        float b2j = b2[j];
        float sc = g2[j] * rsqrtf(rv2[j] + 1e-5f);
        float sh = be2[j] - rm2[j] * sc;
        float bpj = bp[j];
        #pragma unroll
        for (int i = 0; i < 4; ++i) {
            int r = rbase + quad * 4 + i;
            float z = fmaxf((acc2[i] + b2j) * sc + sh, 0.f);
            float p = accp[i] + bpj;
            out[(size_t)r * NCLS + j] = (p + z) * 0.5f;
        }
    }
}

extern "C" void kernel_launch(void* const* d_in, const int* in_sizes, int n_in,
                              void* d_out, int out_size, void* d_ws, size_t ws_size,
                              hipStream_t stream) {
    const float* h    = (const float*)d_in[0];
    const int* esrc   = (const int*)d_in[1];
    const int* edst   = (const int*)d_in[2];
    const float* mask = (const float*)d_in[3];
    const float* w0   = (const float*)d_in[4];
    const float* b0   = (const float*)d_in[5];
    const float* g0   = (const float*)d_in[6];
    const float* be0  = (const float*)d_in[7];
    const float* rm0  = (const float*)d_in[8];
    const float* rv0  = (const float*)d_in[9];
    const float* w1   = (const float*)d_in[10];
    const float* b1   = (const float*)d_in[11];
    const float* g1   = (const float*)d_in[12];
    const float* be1  = (const float*)d_in[13];
    const float* rm1  = (const float*)d_in[14];
    const float* rv1  = (const float*)d_in[15];
    const float* w2   = (const float*)d_in[16];
    const float* b2   = (const float*)d_in[17];
    const float* g2   = (const float*)d_in[18];
    const float* be2  = (const float*)d_in[19];
    const float* rm2  = (const float*)d_in[20];
    const float* rv2  = (const float*)d_in[21];
    const float* wp   = (const float*)d_in[22];
    const float* bp   = (const float*)d_in[23];

    char* ws = (char*)d_ws;
    size_t off = 0;
    auto alloc = [&](size_t bytes) {
        char* p = ws + off;
        off = (off + bytes + 255) & ~(size_t)255;
        return p;
    };
    int* rs       = (int*)alloc(N_PAD * 4);
    int* deg      = (int*)alloc(N_PAD * 4);
    float* dinv   = (float*)alloc(N_PAD * 4);
    int* partial  = (int*)alloc(128 * 4);
    unsigned* segsum = (unsigned*)alloc((size_t)NSEG * 2 * WHALF * 4);
    unsigned* segoff = (unsigned*)alloc((size_t)NSEG * 2 * WHALF * 4);
    unsigned* csr = (unsigned*)alloc((size_t)N_EDGES * 4);
    unsigned* cnt = (unsigned*)alloc((size_t)2 * NCHUNK * WHALF * 4);  // 6.4 MB
    unsigned short* xb16   = (unsigned short*)alloc((size_t)N_NODES * DIM * 2);
    unsigned short* hbA_hi = (unsigned short*)alloc((size_t)N_NODES * DIM * 2);
    unsigned short* hbA_lo = (unsigned short*)alloc((size_t)N_NODES * DIM * 2);
    unsigned short* hbB_hi = (unsigned short*)alloc((size_t)N_NODES * DIM * 2);
    unsigned short* hbB_lo = (unsigned short*)alloc((size_t)N_NODES * DIM * 2);
    unsigned short* f0h = (unsigned short*)alloc(16384 * 2);
    unsigned short* f0l = (unsigned short*)alloc(16384 * 2);
    unsigned short* f1h = (unsigned short*)alloc(16384 * 2);
    unsigned short* f1l = (unsigned short*)alloc(16384 * 2);
    unsigned short* f2h = (unsigned short*)alloc(6144 * 2);
    unsigned short* f2l = (unsigned short*)alloc(6144 * 2);
    unsigned short* fph = (unsigned short*)alloc(6144 * 2);
    unsigned short* fpl = (unsigned short*)alloc(6144 * 2);

    const int GB16 = N_NODES / 16;   // 3125, exact

    prep<<<PREP_B + REPACK_B + CNT_B, 256, 0, stream>>>(
        h, xb16, w0, w1, w2, wp,
        f0h, f0l, f1h, f1l, f2h, f2l, fph, fpl,
        edst, cnt, partial);
    cscan_seg<<<SCAN_B * NSEG, 256, 0, stream>>>(cnt, segsum, partial);
    scan_final<<<SCAN_B, 256, 0, stream>>>(segsum, segoff, partial, rs, deg, dinv);
    fill2<<<dim3(NCHUNK, 2), 256, 0, stream>>>(esrc, edst, mask, cnt, segoff, rs, csr);

    // layer 0: residual from f32 input h; gather from xb16 -> hbA hi/lo
    fused_layer<true><<<GB16, 256, 0, stream>>>(xb16, h, xb16, rs, deg, dinv, csr,
                                                f0h, f0l, b0, g0, be0, rm0, rv0,
                                                hbA_hi, hbA_lo);
    // layer 1: residual + gather from hbA hi/lo -> hbB hi/lo (double-buffered)
    fused_layer<false><<<GB16, 256, 0, stream>>>(hbA_hi, h, hbA_lo, rs, deg, dinv, csr,
                                                 f1h, f1l, b1, g1, be1, rm1, rv1,
                                                 hbB_hi, hbB_lo);
    // layer 2 + predict, fused: hbB hi/lo -> d_out
    fused_final2<<<GB16, 256, 0, stream>>>(hbB_hi, hbB_lo, rs, deg, dinv, csr,
                                           f2h, f2l, fph, fpl,
                                           b2, g2, be2, rm2, rv2, bp, (float*)d_out);
}

// Round 11
// 294.229 us; speedup vs baseline: 1.0328x; 1.0328x over previous
//
#include <hip/hip_runtime.h>

#define N_NODES 50000
#define N_EDGES 800000
#define DIM 128
#define NCLS 40

// chunked CSR build (R9-proven geometry: 256 fill2 blocks = 1/CU)
#define NCHUNK 128
#define CE 6250            // NCHUNK*CE == N_EDGES exactly
#define HALF_N 25088       // nodes per half (2*WHALF)
#define WHALF 12544        // packed u32 words per half (= 49*256)
#define SCAN_B 98          // scan blocks (2 halves * 49)
#define NSEG 4             // chunk-axis segments
#define SEGC 32            // NCHUNK / NSEG
#define N_PAD 50432        // >= 2*HALF_N padded node arrays

typedef __bf16 bf16x8_t __attribute__((ext_vector_type(8)));
typedef unsigned short us8_t __attribute__((ext_vector_type(8)));
typedef float f32x4_t __attribute__((ext_vector_type(4)));

static __device__ __forceinline__ float b2f(unsigned short h) {
    unsigned u = ((unsigned)h) << 16;
    return __builtin_bit_cast(float, u);
}
static __device__ __forceinline__ unsigned short f2b(float f) {
    unsigned u = __builtin_bit_cast(unsigned, f);
    u += 0x7FFFu + ((u >> 16) & 1u);   // RNE; values finite O(1)
    return (unsigned short)(u >> 16);
}

// ---------------- merged prep: bf16 shadow + weight repack + chunk_count ----------------
// blocks [0,3125): to_bf16 of h            [no LDS use]
// blocks [3125,3301): weight repack        [no LDS use]
// blocks [3301,3557): chunk_count          [50 KB LDS]
// R10 lesson kept: the merge is fine; the NCHUNK=64 fill2 de-parallelization was not.
#define PREP_B 3125
#define REPACK_B 176
#define CNT_B 256          // NCHUNK * 2 halves
__global__ __launch_bounds__(256) void prep(const float* __restrict__ hsrc,
                                            unsigned short* __restrict__ hout,
                                            const float* __restrict__ w0,
                                            const float* __restrict__ w1,
                                            const float* __restrict__ w2,
                                            const float* __restrict__ wp,
                                            unsigned short* __restrict__ f0h,
                                            unsigned short* __restrict__ f0l,
                                            unsigned short* __restrict__ f1h,
                                            unsigned short* __restrict__ f1l,
                                            unsigned short* __restrict__ f2h,
                                            unsigned short* __restrict__ f2l,
                                            unsigned short* __restrict__ fph,
                                            unsigned short* __restrict__ fpl,
                                            const int* __restrict__ edst,
                                            unsigned* __restrict__ cnt,
                                            int* __restrict__ partial) {
    __shared__ unsigned lds[WHALF];   // 50 KB (used only by count blocks)
    if (blockIdx.x < PREP_B) {
        size_t e0 = ((size_t)blockIdx.x * 256 + threadIdx.x) * 8;
        f32x4_t v0 = *(const f32x4_t*)(hsrc + e0);
        f32x4_t v1 = *(const f32x4_t*)(hsrc + e0 + 4);
        us8_t o;
        #pragma unroll
        for (int j = 0; j < 4; ++j) { o[j] = f2b(v0[j]); o[4 + j] = f2b(v1[j]); }
        *(us8_t*)(hout + e0) = o;
        return;
    }
    if (blockIdx.x >= PREP_B + REPACK_B) {
        // ---- chunk_count ----
        int cc = blockIdx.x - PREP_B - REPACK_B;   // [0,256)
        int c = cc & (NCHUNK - 1), h = cc >> 7, tid = threadIdx.x;
        if (cc == 0 && tid < 128) partial[tid] = 0;
        for (int w = tid; w < WHALF; w += 256) lds[w] = 0;
        __syncthreads();
        int base = c * CE;
        for (int k = tid; k < CE; k += 256) {
            int local = edst[base + k] - h * HALF_N;
            if (local >= 0 && local < HALF_N)
                atomicAdd(&lds[local >> 1], 1u << ((local & 1) * 16));
        }
        __syncthreads();
        unsigned* out = cnt + ((size_t)(h * NCHUNK + c)) * WHALF;
        for (int w = tid; w < WHALF; w += 256) out[w] = lds[w];
        return;
    }
    // ---- weight repack ----
    int t = (blockIdx.x - PREP_B) * 256 + threadIdx.x;
    const float* src;
    unsigned short *dh, *dl;
    int idx, ncols;
    if (t < 16384)      { src = w0; dh = f0h; dl = f0l; idx = t;         ncols = 128; }
    else if (t < 32768) { src = w1; dh = f1h; dl = f1l; idx = t - 16384; ncols = 128; }
    else if (t < 38912) { src = w2; dh = f2h; dl = f2l; idx = t - 32768; ncols = 48; }
    else if (t < 45056) { src = wp; dh = fph; dl = fpl; idx = t - 38912; ncols = 48; }
    else return;
    int k = idx / ncols, n = idx - k * ncols;
    float v;
    if (ncols == 128) v = src[k * 128 + n];
    else              v = (n < NCLS) ? src[k * NCLS + n] : 0.f;
    int nt = n >> 4, m = n & 15, kt = k >> 5, quad = (k >> 3) & 3, j = k & 7;
    int off = ((nt * 4 + kt) * 64 + quad * 16 + m) * 8 + j;
    unsigned short hi = f2b(v);
    dh[off] = hi;
    dl[off] = f2b(v - b2f(hi));
}

// ---------------- segmented scan over chunk axis: 392 blocks, 32-iter chains ----------------
__global__ __launch_bounds__(256) void cscan_seg(unsigned* __restrict__ cnt,
                                                 unsigned* __restrict__ segsum,
                                                 int* __restrict__ partial) {
    int bx = blockIdx.x;
    int seg = bx / SCAN_B;
    int b = bx - seg * SCAN_B;
    int h = b / 49;
    int w = (b % 49) * 256 + threadIdx.x;
    unsigned acc = 0;
    int c0 = seg * SEGC;
    for (int c = c0; c < c0 + SEGC; ++c) {
        size_t idx = ((size_t)(h * NCHUNK + c)) * WHALF + w;
        unsigned v = cnt[idx];
        cnt[idx] = acc;          // segment-local exclusive prefix (packed halves)
        acc += v;
    }
    segsum[((size_t)(seg * 2 + h)) * WHALF + w] = acc;
    __shared__ int lds[256];
    lds[threadIdx.x] = (int)(acc & 0xFFFFu) + (int)(acc >> 16);
    __syncthreads();
    #pragma unroll
    for (int off = 128; off > 0; off >>= 1) {
        if (threadIdx.x < off) lds[threadIdx.x] += lds[threadIdx.x + off];
        __syncthreads();
    }
    if (threadIdx.x == 0) atomicAdd(&partial[b], lds[0]);
}

// ---------------- final node-axis scan: seg prefix -> segoff; rs / deg / dinv ----------------
__global__ __launch_bounds__(256) void scan_final(const unsigned* __restrict__ segsum,
                                                  unsigned* __restrict__ segoff,
                                                  const int* __restrict__ partial,
                                                  int* __restrict__ rs,
                                                  int* __restrict__ deg,
                                                  float* __restrict__ dinv) {
    __shared__ int lds[256];
    int b = blockIdx.x;
    int h = b / 49;
    int tid = threadIdx.x;
    int w = (b % 49) * 256 + tid;
    lds[tid] = (tid < b && tid < 128) ? partial[tid] : 0;
    __syncthreads();
    #pragma unroll
    for (int off = 128; off > 0; off >>= 1) {
        if (tid < off) lds[tid] += lds[tid + off];
        __syncthreads();
    }
    int boff = lds[0];
    __syncthreads();
    // segment prefix (packed u16 halves; per-node total < 2^16 so no cross-carry)
    unsigned run = 0;
    #pragma unroll
    for (int s = 0; s < NSEG; ++s) {
        unsigned sv = segsum[((size_t)(s * 2 + h)) * WHALF + w];
        segoff[((size_t)(s * 2 + h)) * WHALF + w] = run;
        run += sv;
    }
    unsigned dp = run;
    int lo = (int)(dp & 0xFFFFu), hi = (int)(dp >> 16);
    int s = lo + hi;
    lds[tid] = s;
    __syncthreads();
    #pragma unroll
    for (int off = 1; off < 256; off <<= 1) {
        int v = lds[tid];
        int add = (tid >= off) ? lds[tid - off] : 0;
        __syncthreads();
        lds[tid] = v + add;
        __syncthreads();
    }
    int excl = boff + lds[tid] - s;
    int n0 = h * HALF_N + 2 * w;
    rs[n0] = excl;
    rs[n0 + 1] = excl + lo;
    deg[n0] = lo;
    deg[n0 + 1] = hi;
    dinv[n0] = (lo > 0) ? (1.0f / (float)lo) : 0.0f;
    dinv[n0 + 1] = (hi > 0) ? (1.0f / (float)hi) : 0.0f;
}

// ---------------- CSR fill: rank via LDS returning atomics; blockIdx.y = half ----------------
__global__ __launch_bounds__(256) void fill2(const int* __restrict__ src,
                                             const int* __restrict__ dst,
                                             const float* __restrict__ mask,
                                             const unsigned* __restrict__ cnt,
                                             const unsigned* __restrict__ segoff,
                                             const int* __restrict__ rs,
                                             unsigned* __restrict__ csr) {
    __shared__ unsigned cur[WHALF];   // 50 KB
    int c = blockIdx.x, h = blockIdx.y, tid = threadIdx.x;
    int seg = c >> 5;                 // c / SEGC (SEGC=32)
    const unsigned* off = cnt + ((size_t)(h * NCHUNK + c)) * WHALF;
    const unsigned* soff = segoff + ((size_t)(seg * 2 + h)) * WHALF;
    for (int w = tid; w < WHALF; w += 256) cur[w] = off[w] + soff[w];  // packed add, no carry
    __syncthreads();
    int base = c * CE;
    for (int k = tid; k < CE; k += 256) {
        int e = base + k;
        int d = dst[e];
        int local = d - h * HALF_N;
        if (local >= 0 && local < HALF_N) {
            unsigned sm = (unsigned)src[e] | ((unsigned)f2b(mask[e]) << 16);
            int sh = (local & 1) * 16;
            unsigned old = atomicAdd(&cur[local >> 1], 1u << sh);
            int rank = (int)((old >> sh) & 0xFFFFu);
            csr[rs[d] + rank] = sm;
        }
    }
}

// ---------------- gather primitives ----------------
static __device__ __forceinline__ void issue16(const unsigned short* __restrict__ xb,
                                               unsigned pk, int lane, unsigned* vv) {
    #pragma unroll
    for (int j = 0; j < 16; ++j) {
        unsigned p = (unsigned)__builtin_amdgcn_readlane((int)pk, j);  // 0 for j>=nb
        vv[j] = *(const unsigned*)(xb + (size_t)(p & 0xFFFFu) * DIM + lane * 2);
    }
}
static __device__ __forceinline__ void accum16(unsigned pk, const unsigned* vv,
                                               float& acc0, float& acc1) {
    #pragma unroll
    for (int j = 0; j < 16; ++j) {
        unsigned p = (unsigned)__builtin_amdgcn_readlane((int)pk, j);
        float mm = b2f((unsigned short)(p >> 16));                     // 0 for j>=nb
        acc0 += mm * b2f((unsigned short)(vv[j] & 0xFFFFu));
        acc1 += mm * b2f((unsigned short)(vv[j] >> 16));
    }
}

// ---------------- software-pipelined gather of 4 consecutive nodes into LDS ----------------
template<bool RES32>
static __device__ __forceinline__ void gather4(const unsigned short* __restrict__ xb,
                                               const float* __restrict__ xres,
                                               const unsigned short* __restrict__ xlo,
                                               const int* __restrict__ rs,
                                               const int* __restrict__ deg,
                                               const float* __restrict__ dinv,
                                               const unsigned* __restrict__ csr,
                                               int nb0, int lane,
                                               float (*ldsrow)[132], int row0) {
    int rs4[4], dg4[4];
    float di4[4];
    #pragma unroll
    for (int i = 0; i < 4; ++i) {
        int n = nb0 + i;
        rs4[i] = rs[n];
        dg4[i] = deg[n];
        di4[i] = dinv[n];
    }
    unsigned pk0, pk1, pk2, pk3;
    pk0 = (lane < (dg4[0] < 16 ? dg4[0] : 16)) ? csr[rs4[0] + lane] : 0u;
    pk1 = (lane < (dg4[1] < 16 ? dg4[1] : 16)) ? csr[rs4[1] + lane] : 0u;

    unsigned vvA[16], vvB[16];
    issue16(xb, pk0, lane, vvA);       // node 0 features in flight

    unsigned pkq[4] = {pk0, pk1, 0u, 0u};
    #pragma unroll
    for (int i = 0; i < 4; ++i) {
        if (i == 0) pk2 = (lane < (dg4[2] < 16 ? dg4[2] : 16)) ? csr[rs4[2] + lane] : 0u;
        if (i == 1) pk3 = (lane < (dg4[3] < 16 ? dg4[3] : 16)) ? csr[rs4[3] + lane] : 0u;
        if (i == 0) pkq[2] = pk2;
        if (i == 1) pkq[3] = pk3;
        if (i < 3) issue16(xb, pkq[i + 1], lane, (i & 1) ? vvA : vvB);  // next node in flight
        float acc0 = 0.f, acc1 = 0.f;
        accum16(pkq[i], (i & 1) ? vvB : vvA, acc0, acc1);
        // extra chunks (deg > 16), serial (rarer path)
        for (int base = 16; base < dg4[i]; base += 16) {
            int nb = dg4[i] - base;
            if (nb > 16) nb = 16;
            unsigned pke = (lane < nb) ? csr[rs4[i] + base + lane] : 0u;
            unsigned vvE[16];
            issue16(xb, pke, lane, vvE);
            accum16(pke, vvE, acc0, acc1);
        }
        float di = di4[i];
        float x0, x1;
        if constexpr (RES32) {
            float2 xp = *(const float2*)(xres + (size_t)(nb0 + i) * DIM + lane * 2);
            x0 = xp.x; x1 = xp.y;
        } else {
            unsigned hv = *(const unsigned*)(xb  + (size_t)(nb0 + i) * DIM + lane * 2);
            unsigned lv = *(const unsigned*)(xlo + (size_t)(nb0 + i) * DIM + lane * 2);
            x0 = b2f((unsigned short)(hv & 0xFFFFu)) + b2f((unsigned short)(lv & 0xFFFFu));
            x1 = b2f((unsigned short)(hv >> 16))     + b2f((unsigned short)(lv >> 16));
        }
        ldsrow[row0 + i][lane * 2]     = x0 + acc0 * di;
        ldsrow[row0 + i][lane * 2 + 1] = x1 + acc1 * di;
    }
}

// ---------------- fused agg + GEMM[N,128]x[128,128] + BN + ReLU ----------------
template<bool RES32>
__global__ __launch_bounds__(256) void fused_layer(const unsigned short* __restrict__ xb,
                                                   const float* __restrict__ xres,
                                                   const unsigned short* __restrict__ xlo,
                                                   const int* __restrict__ rs,
                                                   const int* __restrict__ deg,
                                                   const float* __restrict__ dinv,
                                                   const unsigned* __restrict__ csr,
                                                   const unsigned short* __restrict__ wfh,
                                                   const unsigned short* __restrict__ wfl,
                                                   const float* __restrict__ bias,
                                                   const float* __restrict__ gam,
                                                   const float* __restrict__ bet,
                                                   const float* __restrict__ rm,
                                                   const float* __restrict__ rv,
                                                   unsigned short* __restrict__ outhi,
                                                   unsigned short* __restrict__ outlo) {
    __shared__ float lds[16][132];   // 8.4 KB
    int tid = threadIdx.x;
    int wave = tid >> 6, lane = tid & 63;
    int rbase = blockIdx.x * 16;     // 3125 * 16 == 50000 exactly

    gather4<RES32>(xb, xres, xlo, rs, deg, dinv, csr, rbase + wave * 4, lane, lds, wave * 4);
    __syncthreads();   // cross-lane LDS dependency: barrier REQUIRED

    int m = lane & 15, quad = lane >> 4;
    const float* ap = &lds[m][0];

    us8_t ah[4], al[4];
    #pragma unroll
    for (int kt = 0; kt < 4; ++kt) {
        f32x4_t p0 = *(const f32x4_t*)(ap + kt * 32 + quad * 8);
        f32x4_t p1 = *(const f32x4_t*)(ap + kt * 32 + quad * 8 + 4);
        #pragma unroll
        for (int j = 0; j < 4; ++j) {
            unsigned short h0 = f2b(p0[j]);
            unsigned short h1 = f2b(p1[j]);
            ah[kt][j] = h0;
            ah[kt][4 + j] = h1;
            al[kt][j] = f2b(p0[j] - b2f(h0));
            al[kt][4 + j] = f2b(p1[j] - b2f(h1));
        }
    }

    f32x4_t acc[2] = {};
    #pragma unroll
    for (int kt = 0; kt < 4; ++kt) {
        #pragma unroll
        for (int t = 0; t < 2; ++t) {
            int nt = wave * 2 + t;
            int boff = ((nt * 4 + kt) * 64 + lane) * 8;
            us8_t bh = *(const us8_t*)(wfh + boff);
            us8_t bl = *(const us8_t*)(wfl + boff);
            acc[t] = __builtin_amdgcn_mfma_f32_16x16x32_bf16(
                __builtin_bit_cast(bf16x8_t, ah[kt]),
                __builtin_bit_cast(bf16x8_t, bh), acc[t], 0, 0, 0);
            acc[t] = __builtin_amdgcn_mfma_f32_16x16x32_bf16(
                __builtin_bit_cast(bf16x8_t, ah[kt]),
                __builtin_bit_cast(bf16x8_t, bl), acc[t], 0, 0, 0);
            acc[t] = __builtin_amdgcn_mfma_f32_16x16x32_bf16(
                __builtin_bit_cast(bf16x8_t, al[kt]),
                __builtin_bit_cast(bf16x8_t, bh), acc[t], 0, 0, 0);
        }
    }

    #pragma unroll
    for (int t = 0; t < 2; ++t) {
        int nt = wave * 2 + t;
        int j = nt * 16 + m;
        float bj = bias[j];
        float sc = gam[j] * rsqrtf(rv[j] + 1e-5f);
        float sh = bet[j] - rm[j] * sc;
        #pragma unroll
        for (int i = 0; i < 4; ++i) {
            int r = rbase + quad * 4 + i;
            float z = fmaxf((acc[t][i] + bj) * sc + sh, 0.f);
            unsigned short zh = f2b(z);
            outhi[(size_t)r * DIM + j] = zh;
            outlo[(size_t)r * DIM + j] = f2b(z - b2f(zh));
        }
    }
}

// ---------------- fused final ----------------
__global__ __launch_bounds__(256) void fused_final2(const unsigned short* __restrict__ xb,
                                                    const unsigned short* __restrict__ xlo,
                                                    const int* __restrict__ rs,
                                                    const int* __restrict__ deg,
                                                    const float* __restrict__ dinv,
                                                    const unsigned* __restrict__ csr,
                                                    const unsigned short* __restrict__ f2h,
                                                    const unsigned short* __restrict__ f2l,
                                                    const unsigned short* __restrict__ fph,
                                                    const unsigned short* __restrict__ fpl,
                                                    const float* __restrict__ b2,
                                                    const float* __restrict__ g2,
                                                    const float* __restrict__ be2,
                                                    const float* __restrict__ rm2,
                                                    const float* __restrict__ rv2,
                                                    const float* __restrict__ bp,
                                                    float* __restrict__ out) {
    __shared__ float lds[16][132];
    int tid = threadIdx.x;
    int wave = tid >> 6, lane = tid & 63;
    int rbase = blockIdx.x * 16;

    gather4<false>(xb, nullptr, xlo, rs, deg, dinv, csr, rbase + wave * 4, lane, lds, wave * 4);
    __syncthreads();

    if (wave == 3) return;   // waves 0..2 handle the 3 col-tiles

    int m = lane & 15, quad = lane >> 4;
    int arow = rbase + m;
    const float* ap2 = &lds[m][0];
    const unsigned short* aphh = xb  + (size_t)arow * DIM;
    const unsigned short* aphl = xlo + (size_t)arow * DIM;

    us8_t a2h[4], a2l[4], ahh[4], ahl[4];
    #pragma unroll
    for (int kt = 0; kt < 4; ++kt) {
        f32x4_t p0 = *(const f32x4_t*)(ap2 + kt * 32 + quad * 8);
        f32x4_t p1 = *(const f32x4_t*)(ap2 + kt * 32 + quad * 8 + 4);
        ahh[kt] = *(const us8_t*)(aphh + kt * 32 + quad * 8);   // direct hi fragment
        ahl[kt] = *(const us8_t*)(aphl + kt * 32 + quad * 8);   // direct lo fragment
        #pragma unroll
        for (int j = 0; j < 4; ++j) {
            unsigned short h0 = f2b(p0[j]), h1 = f2b(p1[j]);
            a2h[kt][j] = h0; a2h[kt][4 + j] = h1;
            a2l[kt][j] = f2b(p0[j] - b2f(h0));
            a2l[kt][4 + j] = f2b(p1[j] - b2f(h1));
        }
    }

    int nt = wave;           // 0..2
    f32x4_t acc2 = {};
    f32x4_t accp = {};
    #pragma unroll
    for (int kt = 0; kt < 4; ++kt) {
        int boff = ((nt * 4 + kt) * 64 + lane) * 8;
        us8_t b2hv = *(const us8_t*)(f2h + boff);
        us8_t b2lv = *(const us8_t*)(f2l + boff);
        us8_t bphv = *(const us8_t*)(fph + boff);
        us8_t bplv = *(const us8_t*)(fpl + boff);
        acc2 = __builtin_amdgcn_mfma_f32_16x16x32_bf16(
            __builtin_bit_cast(bf16x8_t, a2h[kt]),
            __builtin_bit_cast(bf16x8_t, b2hv), acc2, 0, 0, 0);
        acc2 = __builtin_amdgcn_mfma_f32_16x16x32_bf16(
            __builtin_bit_cast(bf16x8_t, a2h[kt]),
            __builtin_bit_cast(bf16x8_t, b2lv), acc2, 0, 0, 0);
        acc2 = __builtin_amdgcn_mfma_f32_16x16x32_bf16(
            __builtin_bit_cast(bf16x8_t, a2l[kt]),
            __builtin_bit_cast(bf16x8_t, b2hv), acc2, 0, 0, 0);
        accp = __builtin_amdgcn_mfma_f32_16x16x32_bf16(
            __builtin_bit_cast(bf16x8_t, ahh[kt]),
            __builtin_bit_cast(bf16x8_t, bphv), accp, 0, 0, 0);
        accp = __builtin_amdgcn_mfma_f32_16x16x32_bf16(
            __builtin_bit_cast(bf16x8_t, ahh[kt]),
            __builtin_bit_cast(bf16x8_t, bplv), accp, 0, 0, 0);
        accp = __builtin_amdgcn_mfma_f32_16x16x32_bf16(
            __builtin_bit_cast(bf16x8_t, ahl[kt]),
            __builtin_bit_cast(bf16x8_t, bphv), accp, 0, 0, 0);
    }

    int j = nt * 16 + m;
    if (j < NCLS) {
        float b2j = b2[j];
        float sc = g2[j] * rsqrtf(rv2[j] + 1e-5f);
        float sh = be2[j] - rm2[j] * sc;
        float bpj = bp[j];
        #pragma unroll
        for (int i = 0; i < 4; ++i) {
            int r = rbase + quad * 4 + i;
            float z = fmaxf((acc2[i] + b2j) * sc + sh, 0.f);
            float p = accp[i] + bpj;
            out[(size_t)r * NCLS + j] = (p + z) * 0.5f;
        }
    }
}

extern "C" void kernel_launch(void* const* d_in, const int* in_sizes, int n_in,
                              void* d_out, int out_size, void* d_ws, size_t ws_size,
                              hipStream_t stream) {
    const float* h    = (const float*)d_in[0];
    const int* esrc   = (const int*)d_in[1];
    const int* edst   = (const int*)d_in[2];
    const float* mask = (const float*)d_in[3];
    const float* w0   = (const float*)d_in[4];
    const float* b0   = (const float*)d_in[5];
    const float* g0   = (const float*)d_in[6];
    const float* be0  = (const float*)d_in[7];
    const float* rm0  = (const float*)d_in[8];
    const float* rv0  = (const float*)d_in[9];
    const float* w1   = (const float*)d_in[10];
    const float* b1   = (const float*)d_in[11];
    const float* g1   = (const float*)d_in[12];
    const float* be1  = (const float*)d_in[13];
    const float* rm1  = (const float*)d_in[14];
    const float* rv1  = (const float*)d_in[15];
    const float* w2   = (const float*)d_in[16];
    const float* b2   = (const float*)d_in[17];
    const float* g2   = (const float*)d_in[18];
    const float* be2  = (const float*)d_in[19];
    const float* rm2  = (const float*)d_in[20];
    const float* rv2  = (const float*)d_in[21];
    const float* wp   = (const float*)d_in[22];
    const float* bp   = (const float*)d_in[23];

    char* ws = (char*)d_ws;
    size_t off = 0;
    auto alloc = [&](size_t bytes) {
        char* p = ws + off;
        off = (off + bytes + 255) & ~(size_t)255;
        return p;
    };
    int* rs       = (int*)alloc(N_PAD * 4);
    int* deg      = (int*)alloc(N_PAD * 4);
    float* dinv   = (float*)alloc(N_PAD * 4);
    int* partial  = (int*)alloc(128 * 4);
    unsigned* segsum = (unsigned*)alloc((size_t)NSEG * 2 * WHALF * 4);
    unsigned* segoff = (unsigned*)alloc((size_t)NSEG * 2 * WHALF * 4);
    unsigned* csr = (unsigned*)alloc((size_t)N_EDGES * 4);
    unsigned* cnt = (unsigned*)alloc((size_t)2 * NCHUNK * WHALF * 4);  // 12.85 MB
    unsigned short* xb16   = (unsigned short*)alloc((size_t)N_NODES * DIM * 2);
    unsigned short* hbA_hi = (unsigned short*)alloc((size_t)N_NODES * DIM * 2);
    unsigned short* hbA_lo = (unsigned short*)alloc((size_t)N_NODES * DIM * 2);
    unsigned short* hbB_hi = (unsigned short*)alloc((size_t)N_NODES * DIM * 2);
    unsigned short* hbB_lo = (unsigned short*)alloc((size_t)N_NODES * DIM * 2);
    unsigned short* f0h = (unsigned short*)alloc(16384 * 2);
    unsigned short* f0l = (unsigned short*)alloc(16384 * 2);
    unsigned short* f1h = (unsigned short*)alloc(16384 * 2);
    unsigned short* f1l = (unsigned short*)alloc(16384 * 2);
    unsigned short* f2h = (unsigned short*)alloc(6144 * 2);
    unsigned short* f2l = (unsigned short*)alloc(6144 * 2);
    unsigned short* fph = (unsigned short*)alloc(6144 * 2);
    unsigned short* fpl = (unsigned short*)alloc(6144 * 2);

    const int GB16 = N_NODES / 16;   // 3125, exact

    prep<<<PREP_B + REPACK_B + CNT_B, 256, 0, stream>>>(
        h, xb16, w0, w1, w2, wp,
        f0h, f0l, f1h, f1l, f2h, f2l, fph, fpl,
        edst, cnt, partial);
    cscan_seg<<<SCAN_B * NSEG, 256, 0, stream>>>(cnt, segsum, partial);
    scan_final<<<SCAN_B, 256, 0, stream>>>(segsum, segoff, partial, rs, deg, dinv);
    fill2<<<dim3(NCHUNK, 2), 256, 0, stream>>>(esrc, edst, mask, cnt, segoff, rs, csr);

    // layer 0: residual from f32 input h; gather from xb16 -> hbA hi/lo
    fused_layer<true><<<GB16, 256, 0, stream>>>(xb16, h, xb16, rs, deg, dinv, csr,
                                                f0h, f0l, b0, g0, be0, rm0, rv0,
                                                hbA_hi, hbA_lo);
    // layer 1: residual + gather from hbA hi/lo -> hbB hi/lo (double-buffered)
    fused_layer<false><<<GB16, 256, 0, stream>>>(hbA_hi, h, hbA_lo, rs, deg, dinv, csr,
                                                 f1h, f1l, b1, g1, be1, rm1, rv1,
                                                 hbB_hi, hbB_lo);
    // layer 2 + predict, fused: hbB hi/lo -> d_out
    fused_final2<<<GB16, 256, 0, stream>>>(hbB_hi, hbB_lo, rs, deg, dinv, csr,
                                           f2h, f2l, fph, fpl,
                                           b2, g2, be2, rm2, rv2, bp, (float*)d_out);
}